// Round 4
// baseline (318.312 us; speedup 1.0000x reference)
//
#include <hip/hip_runtime.h>
#include <hip/hip_bf16.h>

typedef unsigned short u16;
typedef float f32x4 __attribute__((ext_vector_type(4)));
typedef __bf16 bf16x8 __attribute__((ext_vector_type(8)));

#define BB 4
#define SS 2048
#define DD 1024
#define HH 16
#define HDD 64
#define MM (BB*SS)   // 8192

__device__ __forceinline__ u16 f2bf(float f){
    union { float f; unsigned int i; } v; v.f = f;
    unsigned int i = v.i;
    return (u16)((i + 0x7FFFu + ((i >> 16) & 1u)) >> 16);
}
__device__ __forceinline__ ushort2 pk2(float a, float b){
    union { __hip_bfloat162 h; ushort2 u; } v;
    float2 t; t.x = a; t.y = b;
    v.h = __float22bfloat162_rn(t);
    return v.u;
}
__device__ __forceinline__ ushort4 pk4(float a, float b, float c, float d){
    ushort2 lo = pk2(a, b), hi = pk2(c, d);
    ushort4 r; r.x = lo.x; r.y = lo.y; r.z = hi.x; r.w = hi.y;
    return r;
}
__device__ __forceinline__ void gl2lds16(const void* g, void* l){
    __builtin_amdgcn_global_load_lds(
        (const __attribute__((address_space(1))) void*)g,
        (__attribute__((address_space(3))) void*)l, 16, 0, 0);
}

__device__ __forceinline__ void cvt8(const float* __restrict__ src,
                                     u16* __restrict__ dst, size_t i)
{
    const float4 a = *(const float4*)&src[i];
    const float4 b = *(const float4*)&src[i + 4];
    ushort4 lo = pk4(a.x, a.y, a.z, a.w);
    ushort4 hi = pk4(b.x, b.y, b.z, b.w);
    uint4 o;
    o.x = (unsigned)lo.x | ((unsigned)lo.y << 16);
    o.y = (unsigned)lo.z | ((unsigned)lo.w << 16);
    o.z = (unsigned)hi.x | ((unsigned)hi.y << 16);
    o.w = (unsigned)hi.z | ((unsigned)hi.w << 16);
    *(uint4*)&dst[i] = o;
}

// ---------------- x fp32 -> bf16 pre-convert ----------------
__global__ __launch_bounds__(256) void cvt_k(const float* __restrict__ src,
                                             u16* __restrict__ dst)
{
    const size_t i = ((size_t)blockIdx.x * 256 + threadIdx.x) * 8;
    cvt8(src, dst, i);
}

// ---------------- Wq/Wk/Wv fp32 -> bf16 into d_out scratch (R14) ----------------
// d_out (32 MB) is dead until gemm_out_k; use it so the WB path ALWAYS runs
// (ws_size turned out to be exactly the 64 MB of activation buffers).
__global__ __launch_bounds__(256) void cvtw3_k(
    const float* __restrict__ W0, const float* __restrict__ W1,
    const float* __restrict__ W2, u16* __restrict__ dst)
{
    const float* src = blockIdx.y == 0 ? W0 : (blockIdx.y == 1 ? W1 : W2);
    u16* d = dst + (size_t)blockIdx.y * (size_t)DD * DD;
    const size_t i = ((size_t)blockIdx.x * 256 + threadIdx.x) * 8;
    cvt8(src, d, i);
}

// Wo -> bf16 (runs after attn_k, into the then-dead Q buffer)
__global__ __launch_bounds__(256) void cvtw1_k(const float* __restrict__ W,
                                               u16* __restrict__ dst)
{
    const size_t i = ((size_t)blockIdx.x * 256 + threadIdx.x) * 8;
    cvt8(W, dst, i);
}

// ---------------- GEMM core: C[128,128] tile, pure m97 shape ----------------
// A bf16 [M,K], Wb bf16 [N,K]; both staged via global_load_lds width=16.
__device__ __forceinline__ void gemm_core(const u16* __restrict__ A,
                                          const u16* __restrict__ Wb,
                                          f32x4 (&acc)[4][4],
                                          u16* At, u16* Bt,
                                          int m0, int n0, int tid)
{
    const int lane = tid & 63, w = tid >> 6;
    const int quad = lane >> 4, l15 = lane & 15;
    const int wm = w >> 1, wn = w & 1;
    const int arow = lane >> 2;          // 0..15 within chunk
    const int acol = (lane & 3) * 8;     // element offset (16B)

    for (int k0 = 0; k0 < DD; k0 += 32) {
        __syncthreads();
        #pragma unroll
        for (int c = 0; c < 2; ++c) {
            const int ch = w * 2 + c;     // wave-uniform
            gl2lds16(&A[(size_t)(m0 + ch * 16 + arow) * DD + k0 + acol], &At[ch * 512]);
        }
        #pragma unroll
        for (int c = 0; c < 2; ++c) {
            const int ch = w * 2 + c;
            gl2lds16(&Wb[(size_t)(n0 + ch * 16 + arow) * DD + k0 + acol], &Bt[ch * 512]);
        }
        __syncthreads();
        bf16x8 af[4], bfr[4];
        #pragma unroll
        for (int i = 0; i < 4; ++i)
            af[i] = *(const bf16x8*)&At[(wm * 64 + i * 16 + l15) * 32 + quad * 8];
        #pragma unroll
        for (int j = 0; j < 4; ++j)
            bfr[j] = *(const bf16x8*)&Bt[(wn * 64 + j * 16 + l15) * 32 + quad * 8];
        #pragma unroll
        for (int i = 0; i < 4; ++i)
            #pragma unroll
            for (int j = 0; j < 4; ++j)
                acc[i][j] = __builtin_amdgcn_mfma_f32_16x16x32_bf16(af[i], bfr[j], acc[i][j], 0, 0, 0);
    }
}

// QKV projection: z selects q/k/v; output scattered to [B,H,S,HD] (bf16)
__global__ __launch_bounds__(256, 4) void gemm_qkv_k(
    const u16* __restrict__ x,
    const float* __restrict__ bq, const float* __restrict__ bk,
    const float* __restrict__ bv,
    const u16* __restrict__ Wqb, const u16* __restrict__ Wkb,
    const u16* __restrict__ Wvb,
    u16* __restrict__ Q, u16* __restrict__ K, u16* __restrict__ V)
{
    __shared__ alignas(16) u16 At[128 * 32];
    __shared__ alignas(16) u16 Bt[128 * 32];
    const int tid = threadIdx.x, lane = tid & 63, w = tid >> 6;
    const int quad = lane >> 4, l15 = lane & 15;
    const int wm = w >> 1, wn = w & 1;
    const int z = blockIdx.z;
    const u16* Wmb = z == 0 ? Wqb : (z == 1 ? Wkb : Wvb);
    const float* bias = z == 0 ? bq : (z == 1 ? bk : bv);
    u16* Out = z == 0 ? Q : (z == 1 ? K : V);
    const int m0 = blockIdx.x * 128, n0 = blockIdx.y * 128;

    f32x4 acc[4][4];
    #pragma unroll
    for (int i = 0; i < 4; ++i)
        #pragma unroll
        for (int j = 0; j < 4; ++j) acc[i][j] = (f32x4)(0.0f);

    gemm_core(x, Wmb, acc, At, Bt, m0, n0, tid);

    float bs[4];
    #pragma unroll
    for (int j = 0; j < 4; ++j) bs[j] = bias[n0 + wn * 64 + j * 16 + l15];

    const int b = m0 / SS;
    const int h = (n0 + wn * 64) / HDD;
    const size_t base = ((size_t)(b * HH + h)) * SS * HDD;
    #pragma unroll
    for (int i = 0; i < 4; ++i) {
        #pragma unroll
        for (int r = 0; r < 4; ++r) {
            const int s = (m0 % SS) + wm * 64 + i * 16 + quad * 4 + r;
            #pragma unroll
            for (int j = 0; j < 4; ++j) {
                const int hd = j * 16 + l15;
                Out[base + (size_t)s * HDD + hd] = f2bf(acc[i][j][r] + bs[j]);
            }
        }
    }
}

// Output projection: A bf16 [M,K], Wob bf16 [N,K], out fp32 [M,N]
__global__ __launch_bounds__(256, 4) void gemm_out_k(
    const u16* __restrict__ A, const float* __restrict__ bo,
    const u16* __restrict__ Wob, float* __restrict__ Out)
{
    __shared__ alignas(16) u16 At[128 * 32];
    __shared__ alignas(16) u16 Bt[128 * 32];
    const int tid = threadIdx.x, lane = tid & 63, w = tid >> 6;
    const int quad = lane >> 4, l15 = lane & 15;
    const int wm = w >> 1, wn = w & 1;
    const int m0 = blockIdx.x * 128, n0 = blockIdx.y * 128;

    f32x4 acc[4][4];
    #pragma unroll
    for (int i = 0; i < 4; ++i)
        #pragma unroll
        for (int j = 0; j < 4; ++j) acc[i][j] = (f32x4)(0.0f);

    gemm_core(A, Wob, acc, At, Bt, m0, n0, tid);

    float bs[4];
    #pragma unroll
    for (int j = 0; j < 4; ++j) bs[j] = bo[n0 + wn * 64 + j * 16 + l15];

    #pragma unroll
    for (int i = 0; i < 4; ++i) {
        #pragma unroll
        for (int r = 0; r < 4; ++r) {
            const int m = m0 + wm * 64 + i * 16 + quad * 4 + r;
            #pragma unroll
            for (int j = 0; j < 4; ++j) {
                const int n = n0 + wn * 64 + j * 16 + l15;
                Out[(size_t)m * DD + n] = acc[i][j][r] + bs[j];
            }
        }
    }
}

// ---------------- Flash attention, S^T/O^T, QT=256 x 8 waves ----------------
// R13 structure (two-barrier staging, LDP=64 XOR swizzle, 49664 B LDS,
// 3 blocks/CU). R14 adds: wave-uniform skip of fully-causally-masked tiles
// (kt0 >= wave's last row + 1 -> contributes exactly 0; barriers stay outside
// the branch). ~8% of wave-tiles skipped; frees shared pipes for co-resident
// waves.
#define QT 256
#define KT 64
#define LDPV 66

#define LOG2E 1.4426950408889634f

__device__ __forceinline__ int swz128(int row, int bcol){
    return row * 128 + (bcol ^ ((row & 7) << 4));   // byte offset, rows of 128B
}

__global__ __launch_bounds__(512, 3) void attn_k(
    const u16* __restrict__ Q, const u16* __restrict__ K,
    const u16* __restrict__ V, const int* __restrict__ mask,
    u16* __restrict__ AO)
{
    __shared__ alignas(16) u16 QPs[QT * 64];    // 32768 B, swizzled: Q tile then P
    __shared__ alignas(16) u16 Ks[KT * 64];     //  8192 B, swizzled
    __shared__ alignas(16) u16 Vs[HDD * LDPV];  //  8448 B [hd][kpos]
    __shared__ float padf[KT];                  //   256 B (additive bias)
    // total 49664 B -> 3 blocks/CU x 8 waves = 24 waves/CU

    const int tid = threadIdx.x, lane = tid & 63, w = tid >> 6;   // w in 0..7
    const int quad = lane >> 4, l15 = lane & 15;
    const int bh = blockIdx.x;
    const int y = blockIdx.y;
    const int qt = (y < 4) ? (7 - y) : (y - 4);   // pairs (7,0)(6,1)(5,2)(4,3)
    const int b = bh >> 4, h = bh & 15;
    const int q0 = qt * QT;
    const size_t hoff = (size_t)bh * SS * HDD;
    const u16* Qh = Q + hoff;
    const u16* Kh = K + hoff;
    const u16* Vh = V + hoff;
    const int nkt = (q0 + QT) / KT;
    const float scale2 = 0.125f * LOG2E;   // HD^-0.5 folded with log2(e)
    const int wrow_end = q0 + w * 32 + 32; // one past the wave's last q-row

    // stage Q tile (swizzled rows of 128B)
    for (int c = tid; c < QT * 8; c += 512) {
        const int row = c >> 3, cc = c & 7;
        *(uint4*)((char*)QPs + swz128(row, cc * 16)) =
            *(const uint4*)&Qh[(size_t)(q0 + row) * HDD + cc * 8];
    }
    __syncthreads();

    bf16x8 bQ[2][2];
    #pragma unroll
    for (int j = 0; j < 2; ++j)
        #pragma unroll
        for (int ks = 0; ks < 2; ++ks)
            bQ[j][ks] = *(const bf16x8*)((const char*)QPs +
                swz128(w * 32 + j * 16 + l15, ks * 64 + quad * 16));
    // QPs rows w*32..w*32+31 are wave-private from here on.

    float m_run[2] = { -1e30f, -1e30f };
    float l_run[2] = { 0.f, 0.f };     // per-quad partials
    f32x4 o[4][2];
    #pragma unroll
    for (int i = 0; i < 4; ++i)
        #pragma unroll
        for (int j = 0; j < 2; ++j) o[i][j] = (f32x4)(0.0f);

    for (int kt = 0; kt < nkt; ++kt) {
        const int kt0 = kt * KT;
        __syncthreads();   // prior iter's Ks/Vs reads complete

        if (tid < 256) {
            // Ks [kpos][hd] swizzled: 512 uint4 / 256 threads = 2 each
            #pragma unroll
            for (int it = 0; it < 2; ++it) {
                const int c = tid + it * 256;
                const int row = c >> 3, cc = c & 7;
                *(uint4*)((char*)Ks + swz128(row, cc * 16)) =
                    *(const uint4*)&Kh[(size_t)(kt0 + row) * HDD + cc * 8];
            }
        } else if (tid < 384) {
            // Vs [hd][kpos]: pack-4 transpose (128 threads x 4 rows)
            const int t = tid - 256;
            const int kq = t >> 3;
            const int c0 = (t & 7) * 8;
            uint4 r0 = *(const uint4*)&Vh[(size_t)(kt0 + kq * 4 + 0) * HDD + c0];
            uint4 r1 = *(const uint4*)&Vh[(size_t)(kt0 + kq * 4 + 1) * HDD + c0];
            uint4 r2 = *(const uint4*)&Vh[(size_t)(kt0 + kq * 4 + 2) * HDD + c0];
            uint4 r3 = *(const uint4*)&Vh[(size_t)(kt0 + kq * 4 + 3) * HDD + c0];
            const u16* e0 = (const u16*)&r0;
            const u16* e1 = (const u16*)&r1;
            const u16* e2 = (const u16*)&r2;
            const u16* e3 = (const u16*)&r3;
            #pragma unroll
            for (int e = 0; e < 8; ++e) {
                ushort4 pkv; pkv.x = e0[e]; pkv.y = e1[e]; pkv.z = e2[e]; pkv.w = e3[e];
                *(ushort4*)&Vs[(c0 + e) * LDPV + kq * 4] = pkv;
            }
        } else if (tid < 448) {
            const int t = tid - 384;
            padf[t] = (mask[b * SS + kt0 + t] == 0) ? -1e9f : 0.0f;
        }
        __syncthreads();

        if (kt0 < wrow_end) {   // wave-uniform: tile has >=1 unmasked (row,col)
        // S^T = K Q^T : C[kpos = i*16+quad*4+r][qrow = w*32+j*16+l15]
        f32x4 sc[4][2];
        #pragma unroll
        for (int i = 0; i < 4; ++i)
            #pragma unroll
            for (int j = 0; j < 2; ++j) sc[i][j] = (f32x4)(0.0f);
        __builtin_amdgcn_s_setprio(1);
        #pragma unroll
        for (int ks = 0; ks < 2; ++ks) {
            bf16x8 aK[4];
            #pragma unroll
            for (int i = 0; i < 4; ++i)
                aK[i] = *(const bf16x8*)((const char*)Ks +
                    swz128(i * 16 + l15, ks * 64 + quad * 16));
            #pragma unroll
            for (int i = 0; i < 4; ++i)
                #pragma unroll
                for (int j = 0; j < 2; ++j)
                    sc[i][j] = __builtin_amdgcn_mfma_f32_16x16x32_bf16(aK[i], bQ[j][ks], sc[i][j], 0, 0, 0);
        }
        __builtin_amdgcn_s_setprio(0);

        f32x4 pb[4];
        #pragma unroll
        for (int i = 0; i < 4; ++i)
            pb[i] = *(const f32x4*)&padf[i * 16 + quad * 4];

        #pragma unroll
        for (int j = 0; j < 2; ++j) {
            const int qrow = q0 + w * 32 + j * 16 + l15;
            const bool needC = (kt0 + KT - 1) > (q0 + w * 32 + j * 16);  // wave-uniform
            float mx = -1e9f;
            if (needC) {
                #pragma unroll
                for (int i = 0; i < 4; ++i)
                    #pragma unroll
                    for (int r = 0; r < 4; ++r) {
                        const int kpg = kt0 + i * 16 + quad * 4 + r;
                        float s = fmaf(sc[i][j][r], scale2, pb[i][r]);
                        s = (kpg > qrow) ? -1e9f : s;
                        sc[i][j][r] = s; mx = fmaxf(mx, s);
                    }
            } else {
                #pragma unroll
                for (int i = 0; i < 4; ++i)
                    #pragma unroll
                    for (int r = 0; r < 4; ++r) {
                        float s = fmaf(sc[i][j][r], scale2, pb[i][r]);
                        sc[i][j][r] = s; mx = fmaxf(mx, s);
                    }
            }
            mx = fmaxf(mx, __shfl_xor(mx, 16, 64));
            mx = fmaxf(mx, __shfl_xor(mx, 32, 64));
            // defer-max (T13): skip rescale while max grows < 8 (log2 units)
            float nm = m_run[j];
            if (!__all(mx <= nm + 8.f)) {
                nm = fmaxf(nm, mx);
                const float alpha = __builtin_exp2f(m_run[j] - nm);
                m_run[j] = nm;
                l_run[j] *= alpha;
                #pragma unroll
                for (int i = 0; i < 4; ++i)
                    #pragma unroll
                    for (int r = 0; r < 4; ++r) o[i][j][r] *= alpha;
            }
            float rs = 0.f;
            #pragma unroll
            for (int i = 0; i < 4; ++i) {
                float p0 = __builtin_exp2f(sc[i][j][0] - nm);
                float p1 = __builtin_exp2f(sc[i][j][1] - nm);
                float p2 = __builtin_exp2f(sc[i][j][2] - nm);
                float p3 = __builtin_exp2f(sc[i][j][3] - nm);
                rs += (p0 + p1) + (p2 + p3);
                *(ushort4*)((char*)QPs + swz128(w * 32 + j * 16 + l15, i * 32 + quad * 8)) =
                    pk4(p0, p1, p2, p3);
            }
            l_run[j] += rs;
        }
        // same-wave LDS RAW (QPs writes -> bP reads)
        asm volatile("s_waitcnt lgkmcnt(0)" ::: "memory");

        // O^T += V^T P^T : A = Vs[hd][kpos], B = QPs[qrow][kpos]
        __builtin_amdgcn_s_setprio(1);
        #pragma unroll
        for (int ks = 0; ks < 2; ++ks) {
            bf16x8 aV[4], bP[2];
            #pragma unroll
            for (int i = 0; i < 4; ++i)
                aV[i] = *(const bf16x8*)&Vs[(i * 16 + l15) * LDPV + ks * 32 + quad * 8];
            #pragma unroll
            for (int j = 0; j < 2; ++j)
                bP[j] = *(const bf16x8*)((const char*)QPs +
                    swz128(w * 32 + j * 16 + l15, ks * 64 + quad * 16));
            #pragma unroll
            for (int i = 0; i < 4; ++i)
                #pragma unroll
                for (int j = 0; j < 2; ++j)
                    o[i][j] = __builtin_amdgcn_mfma_f32_16x16x32_bf16(aV[i], bP[j], o[i][j], 0, 0, 0);
        }
        __builtin_amdgcn_s_setprio(0);
        }   // if active tile
    }

    // final l reduction across quads, then store O^T -> AO [B,S,H*HD] (bf16)
    #pragma unroll
    for (int j = 0; j < 2; ++j) {
        float l = l_run[j];
        l += __shfl_xor(l, 16, 64);
        l += __shfl_xor(l, 32, 64);
        const float inv = (l > 0.f) ? (1.f / l) : 0.f;
        const int s = q0 + w * 32 + j * 16 + l15;
        const size_t rb = ((size_t)(b * SS + s)) * DD + h * HDD;
        #pragma unroll
        for (int i = 0; i < 4; ++i)
            *(ushort4*)&AO[rb + i * 16 + quad * 4] =
                pk4(o[i][j][0] * inv, o[i][j][1] * inv, o[i][j][2] * inv, o[i][j][3] * inv);
    }
}

extern "C" void kernel_launch(void* const* d_in, const int* in_sizes, int n_in,
                              void* d_out, int out_size, void* d_ws, size_t ws_size,
                              hipStream_t stream)
{
    const float* x  = (const float*)d_in[0];
    const int* mask = (const int*)d_in[1];
    const float* Wq = (const float*)d_in[2];
    const float* bq = (const float*)d_in[3];
    const float* Wk = (const float*)d_in[4];
    const float* bk = (const float*)d_in[5];
    const float* Wv = (const float*)d_in[6];
    const float* bv = (const float*)d_in[7];
    const float* Wo = (const float*)d_in[8];
    const float* bo = (const float*)d_in[9];
    float* out = (float*)d_out;

    u16* ws = (u16*)d_ws;
    const size_t NE = (size_t)MM * DD;
    const size_t WE = (size_t)DD * DD;
    if (ws_size < 4 * NE * sizeof(u16)) return;

    u16* Qb = ws;
    u16* Kb = ws + NE;
    u16* Vb = ws + 2 * NE;
    u16* Ab = ws + 3 * NE;   // x_bf16 first, then attention output (sequential reuse)

    // W bf16 scratch lives in d_out (dead until gemm_out_k overwrites all of it)
    u16* Wscr = (u16*)d_out;          // Wq,Wk,Wv bf16: 3*WE*2 = 6 MB <= 32 MB

    dim3 blk(256);
    cvt_k<<<dim3(NE / 2048), blk, 0, stream>>>(x, Ab);
    cvtw3_k<<<dim3(WE / 2048, 3), blk, 0, stream>>>(Wq, Wk, Wv, Wscr);
    gemm_qkv_k<<<dim3(MM / 128, DD / 128, 3), blk, 0, stream>>>(
        Ab, bq, bk, bv, Wscr, Wscr + WE, Wscr + 2 * WE, Qb, Kb, Vb);
    attn_k<<<dim3(BB * HH, SS / QT), dim3(512), 0, stream>>>(Qb, Kb, Vb, mask, Ab);
    cvtw1_k<<<dim3(WE / 2048), blk, 0, stream>>>(Wo, Qb);   // Q dead; holds Wo bf16
    gemm_out_k<<<dim3(MM / 128, DD / 128), blk, 0, stream>>>(Ab, bo, Qb, out);
}

// Round 5
// 305.692 us; speedup vs baseline: 1.0413x; 1.0413x over previous
//
#include <hip/hip_runtime.h>
#include <hip/hip_bf16.h>

typedef unsigned short u16;
typedef float f32x4 __attribute__((ext_vector_type(4)));
typedef __bf16 bf16x8 __attribute__((ext_vector_type(8)));

#define BB 4
#define SS 2048
#define DD 1024
#define HH 16
#define HDD 64
#define MM (BB*SS)   // 8192

__device__ __forceinline__ u16 f2bf(float f){
    union { float f; unsigned int i; } v; v.f = f;
    unsigned int i = v.i;
    return (u16)((i + 0x7FFFu + ((i >> 16) & 1u)) >> 16);
}
__device__ __forceinline__ ushort2 pk2(float a, float b){
    union { __hip_bfloat162 h; ushort2 u; } v;
    float2 t; t.x = a; t.y = b;
    v.h = __float22bfloat162_rn(t);
    return v.u;
}
__device__ __forceinline__ ushort4 pk4(float a, float b, float c, float d){
    ushort2 lo = pk2(a, b), hi = pk2(c, d);
    ushort4 r; r.x = lo.x; r.y = lo.y; r.z = hi.x; r.w = hi.y;
    return r;
}
__device__ __forceinline__ void gl2lds16(const void* g, void* l){
    __builtin_amdgcn_global_load_lds(
        (const __attribute__((address_space(1))) void*)g,
        (__attribute__((address_space(3))) void*)l, 16, 0, 0);
}

__device__ __forceinline__ void cvt8(const float* __restrict__ src,
                                     u16* __restrict__ dst, size_t i)
{
    const float4 a = *(const float4*)&src[i];
    const float4 b = *(const float4*)&src[i + 4];
    ushort4 lo = pk4(a.x, a.y, a.z, a.w);
    ushort4 hi = pk4(b.x, b.y, b.z, b.w);
    uint4 o;
    o.x = (unsigned)lo.x | ((unsigned)lo.y << 16);
    o.y = (unsigned)lo.z | ((unsigned)lo.w << 16);
    o.z = (unsigned)hi.x | ((unsigned)hi.y << 16);
    o.w = (unsigned)hi.z | ((unsigned)hi.w << 16);
    *(uint4*)&dst[i] = o;
}

// ---------------- x fp32 -> bf16 pre-convert ----------------
__global__ __launch_bounds__(256) void cvt_k(const float* __restrict__ src,
                                             u16* __restrict__ dst)
{
    const size_t i = ((size_t)blockIdx.x * 256 + threadIdx.x) * 8;
    cvt8(src, dst, i);
}

// ---------------- Wq/Wk/Wv fp32 -> bf16 into d_out scratch ----------------
__global__ __launch_bounds__(256) void cvtw3_k(
    const float* __restrict__ W0, const float* __restrict__ W1,
    const float* __restrict__ W2, u16* __restrict__ dst)
{
    const float* src = blockIdx.y == 0 ? W0 : (blockIdx.y == 1 ? W1 : W2);
    u16* d = dst + (size_t)blockIdx.y * (size_t)DD * DD;
    const size_t i = ((size_t)blockIdx.x * 256 + threadIdx.x) * 8;
    cvt8(src, d, i);
}

// Wo -> bf16 (runs after attn_k, into the then-dead Q buffer)
__global__ __launch_bounds__(256) void cvtw1_k(const float* __restrict__ W,
                                               u16* __restrict__ dst)
{
    const size_t i = ((size_t)blockIdx.x * 256 + threadIdx.x) * 8;
    cvt8(W, dst, i);
}

// ---------------- GEMM core: C[128,128] tile, BK=64 (R15) ----------------
// R14 post-mortem: removing the in-loop W convert changed nothing -> the
// limiter is the per-iter barrier drain (vmcnt(0) before each s_barrier),
// 32x per block at BK=32. BK=64 halves barrier pairs: 32 MFMA per pair.
// LDS 2x16KB = 32 KB -> still 4 blocks/CU at 256 threads.
__device__ __forceinline__ void gemm_core(const u16* __restrict__ A,
                                          const u16* __restrict__ Wb,
                                          f32x4 (&acc)[4][4],
                                          u16* At, u16* Bt,
                                          int m0, int n0, int tid)
{
    const int lane = tid & 63, w = tid >> 6;
    const int quad = lane >> 4, l15 = lane & 15;
    const int wm = w >> 1, wn = w & 1;
    const int arow = lane >> 2;          // 0..15 within chunk
    const int acol = (lane & 3) * 8;     // element offset (16B)

    for (int k0 = 0; k0 < DD; k0 += 64) {
        __syncthreads();
        // two 32-col slabs per buffer: slab s at [s*4096 .. ), each chunk
        // ch = 16 rows x 32 elems, lane-linear, wave-uniform dest
        #pragma unroll
        for (int s = 0; s < 2; ++s) {
            #pragma unroll
            for (int c = 0; c < 2; ++c) {
                const int ch = w * 2 + c;
                gl2lds16(&A[(size_t)(m0 + ch * 16 + arow) * DD + k0 + s * 32 + acol],
                         &At[s * 4096 + ch * 512]);
                gl2lds16(&Wb[(size_t)(n0 + ch * 16 + arow) * DD + k0 + s * 32 + acol],
                         &Bt[s * 4096 + ch * 512]);
            }
        }
        __syncthreads();
        #pragma unroll
        for (int s = 0; s < 2; ++s) {
            bf16x8 af[4], bfr[4];
            #pragma unroll
            for (int i = 0; i < 4; ++i)
                af[i] = *(const bf16x8*)&At[s * 4096 + (wm * 64 + i * 16 + l15) * 32 + quad * 8];
            #pragma unroll
            for (int j = 0; j < 4; ++j)
                bfr[j] = *(const bf16x8*)&Bt[s * 4096 + (wn * 64 + j * 16 + l15) * 32 + quad * 8];
            #pragma unroll
            for (int i = 0; i < 4; ++i)
                #pragma unroll
                for (int j = 0; j < 4; ++j)
                    acc[i][j] = __builtin_amdgcn_mfma_f32_16x16x32_bf16(af[i], bfr[j], acc[i][j], 0, 0, 0);
        }
    }
}

// QKV projection: z selects q/k/v; output scattered to [B,H,S,HD] (bf16)
__global__ __launch_bounds__(256, 4) void gemm_qkv_k(
    const u16* __restrict__ x,
    const float* __restrict__ bq, const float* __restrict__ bk,
    const float* __restrict__ bv,
    const u16* __restrict__ Wqb, const u16* __restrict__ Wkb,
    const u16* __restrict__ Wvb,
    u16* __restrict__ Q, u16* __restrict__ K, u16* __restrict__ V)
{
    __shared__ alignas(16) u16 At[128 * 64];
    __shared__ alignas(16) u16 Bt[128 * 64];
    const int tid = threadIdx.x, lane = tid & 63, w = tid >> 6;
    const int quad = lane >> 4, l15 = lane & 15;
    const int wm = w >> 1, wn = w & 1;
    const int z = blockIdx.z;
    const u16* Wmb = z == 0 ? Wqb : (z == 1 ? Wkb : Wvb);
    const float* bias = z == 0 ? bq : (z == 1 ? bk : bv);
    u16* Out = z == 0 ? Q : (z == 1 ? K : V);
    const int m0 = blockIdx.x * 128, n0 = blockIdx.y * 128;

    f32x4 acc[4][4];
    #pragma unroll
    for (int i = 0; i < 4; ++i)
        #pragma unroll
        for (int j = 0; j < 4; ++j) acc[i][j] = (f32x4)(0.0f);

    gemm_core(x, Wmb, acc, At, Bt, m0, n0, tid);

    float bs[4];
    #pragma unroll
    for (int j = 0; j < 4; ++j) bs[j] = bias[n0 + wn * 64 + j * 16 + l15];

    const int b = m0 / SS;
    const int h = (n0 + wn * 64) / HDD;
    const size_t base = ((size_t)(b * HH + h)) * SS * HDD;
    #pragma unroll
    for (int i = 0; i < 4; ++i) {
        #pragma unroll
        for (int r = 0; r < 4; ++r) {
            const int s = (m0 % SS) + wm * 64 + i * 16 + quad * 4 + r;
            #pragma unroll
            for (int j = 0; j < 4; ++j) {
                const int hd = j * 16 + l15;
                Out[base + (size_t)s * HDD + hd] = f2bf(acc[i][j][r] + bs[j]);
            }
        }
    }
}

// Output projection: A bf16 [M,K], Wob bf16 [N,K], out fp32 [M,N]
__global__ __launch_bounds__(256, 4) void gemm_out_k(
    const u16* __restrict__ A, const float* __restrict__ bo,
    const u16* __restrict__ Wob, float* __restrict__ Out)
{
    __shared__ alignas(16) u16 At[128 * 64];
    __shared__ alignas(16) u16 Bt[128 * 64];
    const int tid = threadIdx.x, lane = tid & 63, w = tid >> 6;
    const int quad = lane >> 4, l15 = lane & 15;
    const int wm = w >> 1, wn = w & 1;
    const int m0 = blockIdx.x * 128, n0 = blockIdx.y * 128;

    f32x4 acc[4][4];
    #pragma unroll
    for (int i = 0; i < 4; ++i)
        #pragma unroll
        for (int j = 0; j < 4; ++j) acc[i][j] = (f32x4)(0.0f);

    gemm_core(A, Wob, acc, At, Bt, m0, n0, tid);

    float bs[4];
    #pragma unroll
    for (int j = 0; j < 4; ++j) bs[j] = bo[n0 + wn * 64 + j * 16 + l15];

    #pragma unroll
    for (int i = 0; i < 4; ++i) {
        #pragma unroll
        for (int r = 0; r < 4; ++r) {
            const int m = m0 + wm * 64 + i * 16 + quad * 4 + r;
            #pragma unroll
            for (int j = 0; j < 4; ++j) {
                const int n = n0 + wn * 64 + j * 16 + l15;
                Out[(size_t)m * DD + n] = acc[i][j][r] + bs[j];
            }
        }
    }
}

// ---------------- Flash attention, S^T/O^T, QT=256 x 8 waves ----------------
// R15: shrink the staging window (the ~48%-idle source): K tile staged by ONE
// global_load_lds per wave with inverse-swizzled global source (rule #21:
// linear LDS dest + inverse-swz src == swizzled content; read side unchanged),
// V transpose spread over 256 threads (2 rows each, ushort2 writes, 2-way
// bank = free). Zero extra VGPR/LDS; 3 blocks/CU retained.
#define QT 256
#define KT 64
#define LDPV 66

#define LOG2E 1.4426950408889634f

__device__ __forceinline__ int swz128(int row, int bcol){
    return row * 128 + (bcol ^ ((row & 7) << 4));   // byte offset, rows of 128B
}

__global__ __launch_bounds__(512, 3) void attn_k(
    const u16* __restrict__ Q, const u16* __restrict__ K,
    const u16* __restrict__ V, const int* __restrict__ mask,
    u16* __restrict__ AO)
{
    __shared__ alignas(16) u16 QPs[QT * 64];    // 32768 B, swizzled: Q tile then P
    __shared__ alignas(16) u16 Ks[KT * 64];     //  8192 B, swizzled
    __shared__ alignas(16) u16 Vs[HDD * LDPV];  //  8448 B [hd][kpos]
    __shared__ float padf[KT];                  //   256 B (additive bias)
    // total 49664 B -> 3 blocks/CU x 8 waves = 24 waves/CU

    const int tid = threadIdx.x, lane = tid & 63, w = tid >> 6;   // w in 0..7
    const int quad = lane >> 4, l15 = lane & 15;
    const int bh = blockIdx.x;
    const int y = blockIdx.y;
    const int qt = (y < 4) ? (7 - y) : (y - 4);   // pairs (7,0)(6,1)(5,2)(4,3)
    const int b = bh >> 4, h = bh & 15;
    const int q0 = qt * QT;
    const size_t hoff = (size_t)bh * SS * HDD;
    const u16* Qh = Q + hoff;
    const u16* Kh = K + hoff;
    const u16* Vh = V + hoff;
    const int nkt = (q0 + QT) / KT;
    const float scale2 = 0.125f * LOG2E;   // HD^-0.5 folded with log2(e)
    const int wrow_end = q0 + w * 32 + 32; // one past the wave's last q-row

    // K DMA geometry (constant per thread): slot = w*64+lane, row = slot/8,
    // src byte col inverse-swizzled so that swz128-reads see K[row][col].
    const int kslot = w * 64 + lane;
    const int krow = kslot >> 3;
    const int kbcol = ((kslot & 7) << 4) ^ ((krow & 7) << 4);

    // stage Q tile (swizzled rows of 128B)
    for (int c = tid; c < QT * 8; c += 512) {
        const int row = c >> 3, cc = c & 7;
        *(uint4*)((char*)QPs + swz128(row, cc * 16)) =
            *(const uint4*)&Qh[(size_t)(q0 + row) * HDD + cc * 8];
    }
    __syncthreads();

    bf16x8 bQ[2][2];
    #pragma unroll
    for (int j = 0; j < 2; ++j)
        #pragma unroll
        for (int ks = 0; ks < 2; ++ks)
            bQ[j][ks] = *(const bf16x8*)((const char*)QPs +
                swz128(w * 32 + j * 16 + l15, ks * 64 + quad * 16));
    // QPs rows w*32..w*32+31 are wave-private from here on.

    float m_run[2] = { -1e30f, -1e30f };
    float l_run[2] = { 0.f, 0.f };     // per-quad partials
    f32x4 o[4][2];
    #pragma unroll
    for (int i = 0; i < 4; ++i)
        #pragma unroll
        for (int j = 0; j < 2; ++j) o[i][j] = (f32x4)(0.0f);

    for (int kt = 0; kt < nkt; ++kt) {
        const int kt0 = kt * KT;
        __syncthreads();   // prior iter's Ks/Vs reads complete

        // K: async DMA, 1 instr/wave; barrier-2's vmcnt(0) drains it
        gl2lds16((const char*)Kh + (size_t)(kt0 + krow) * 128 + kbcol,
                 (char*)Ks + w * 1024);

        if (tid < 256) {
            // Vs [hd][kpos]: pack-2 transpose, 256 threads x 2 rows
            const int kp = tid >> 3;            // 0..31 (row pair)
            const int c0 = (tid & 7) * 8;       // hd chunk
            uint4 r0 = *(const uint4*)&Vh[(size_t)(kt0 + kp * 2 + 0) * HDD + c0];
            uint4 r1 = *(const uint4*)&Vh[(size_t)(kt0 + kp * 2 + 1) * HDD + c0];
            const u16* e0 = (const u16*)&r0;
            const u16* e1 = (const u16*)&r1;
            #pragma unroll
            for (int e = 0; e < 8; ++e) {
                ushort2 pkv; pkv.x = e0[e]; pkv.y = e1[e];
                *(ushort2*)&Vs[(c0 + e) * LDPV + kp * 2] = pkv;
            }
        } else if (tid < 320) {
            const int t = tid - 256;
            padf[t] = (mask[b * SS + kt0 + t] == 0) ? -1e9f : 0.0f;
        }
        __syncthreads();

        if (kt0 < wrow_end) {   // wave-uniform: tile has >=1 unmasked (row,col)
        // S^T = K Q^T : C[kpos = i*16+quad*4+r][qrow = w*32+j*16+l15]
        f32x4 sc[4][2];
        #pragma unroll
        for (int i = 0; i < 4; ++i)
            #pragma unroll
            for (int j = 0; j < 2; ++j) sc[i][j] = (f32x4)(0.0f);
        __builtin_amdgcn_s_setprio(1);
        #pragma unroll
        for (int ks = 0; ks < 2; ++ks) {
            bf16x8 aK[4];
            #pragma unroll
            for (int i = 0; i < 4; ++i)
                aK[i] = *(const bf16x8*)((const char*)Ks +
                    swz128(i * 16 + l15, ks * 64 + quad * 16));
            #pragma unroll
            for (int i = 0; i < 4; ++i)
                #pragma unroll
                for (int j = 0; j < 2; ++j)
                    sc[i][j] = __builtin_amdgcn_mfma_f32_16x16x32_bf16(aK[i], bQ[j][ks], sc[i][j], 0, 0, 0);
        }
        __builtin_amdgcn_s_setprio(0);

        f32x4 pb[4];
        #pragma unroll
        for (int i = 0; i < 4; ++i)
            pb[i] = *(const f32x4*)&padf[i * 16 + quad * 4];

        #pragma unroll
        for (int j = 0; j < 2; ++j) {
            const int qrow = q0 + w * 32 + j * 16 + l15;
            const bool needC = (kt0 + KT - 1) > (q0 + w * 32 + j * 16);  // wave-uniform
            float mx = -1e9f;
            if (needC) {
                #pragma unroll
                for (int i = 0; i < 4; ++i)
                    #pragma unroll
                    for (int r = 0; r < 4; ++r) {
                        const int kpg = kt0 + i * 16 + quad * 4 + r;
                        float s = fmaf(sc[i][j][r], scale2, pb[i][r]);
                        s = (kpg > qrow) ? -1e9f : s;
                        sc[i][j][r] = s; mx = fmaxf(mx, s);
                    }
            } else {
                #pragma unroll
                for (int i = 0; i < 4; ++i)
                    #pragma unroll
                    for (int r = 0; r < 4; ++r) {
                        float s = fmaf(sc[i][j][r], scale2, pb[i][r]);
                        sc[i][j][r] = s; mx = fmaxf(mx, s);
                    }
            }
            mx = fmaxf(mx, __shfl_xor(mx, 16, 64));
            mx = fmaxf(mx, __shfl_xor(mx, 32, 64));
            // defer-max (T13): skip rescale while max grows < 8 (log2 units)
            float nm = m_run[j];
            if (!__all(mx <= nm + 8.f)) {
                nm = fmaxf(nm, mx);
                const float alpha = __builtin_exp2f(m_run[j] - nm);
                m_run[j] = nm;
                l_run[j] *= alpha;
                #pragma unroll
                for (int i = 0; i < 4; ++i)
                    #pragma unroll
                    for (int r = 0; r < 4; ++r) o[i][j][r] *= alpha;
            }
            float rs = 0.f;
            #pragma unroll
            for (int i = 0; i < 4; ++i) {
                float p0 = __builtin_exp2f(sc[i][j][0] - nm);
                float p1 = __builtin_exp2f(sc[i][j][1] - nm);
                float p2 = __builtin_exp2f(sc[i][j][2] - nm);
                float p3 = __builtin_exp2f(sc[i][j][3] - nm);
                rs += (p0 + p1) + (p2 + p3);
                *(ushort4*)((char*)QPs + swz128(w * 32 + j * 16 + l15, i * 32 + quad * 8)) =
                    pk4(p0, p1, p2, p3);
            }
            l_run[j] += rs;
        }
        // same-wave LDS RAW (QPs writes -> bP reads)
        asm volatile("s_waitcnt lgkmcnt(0)" ::: "memory");

        // O^T += V^T P^T : A = Vs[hd][kpos], B = QPs[qrow][kpos]
        __builtin_amdgcn_s_setprio(1);
        #pragma unroll
        for (int ks = 0; ks < 2; ++ks) {
            bf16x8 aV[4], bP[2];
            #pragma unroll
            for (int i = 0; i < 4; ++i)
                aV[i] = *(const bf16x8*)&Vs[(i * 16 + l15) * LDPV + ks * 32 + quad * 8];
            #pragma unroll
            for (int j = 0; j < 2; ++j)
                bP[j] = *(const bf16x8*)((const char*)QPs +
                    swz128(w * 32 + j * 16 + l15, ks * 64 + quad * 16));
            #pragma unroll
            for (int i = 0; i < 4; ++i)
                #pragma unroll
                for (int j = 0; j < 2; ++j)
                    o[i][j] = __builtin_amdgcn_mfma_f32_16x16x32_bf16(aV[i], bP[j], o[i][j], 0, 0, 0);
        }
        __builtin_amdgcn_s_setprio(0);
        }   // if active tile
    }

    // final l reduction across quads, then store O^T -> AO [B,S,H*HD] (bf16)
    #pragma unroll
    for (int j = 0; j < 2; ++j) {
        float l = l_run[j];
        l += __shfl_xor(l, 16, 64);
        l += __shfl_xor(l, 32, 64);
        const float inv = (l > 0.f) ? (1.f / l) : 0.f;
        const int s = q0 + w * 32 + j * 16 + l15;
        const size_t rb = ((size_t)(b * SS + s)) * DD + h * HDD;
        #pragma unroll
        for (int i = 0; i < 4; ++i)
            *(ushort4*)&AO[rb + i * 16 + quad * 4] =
                pk4(o[i][j][0] * inv, o[i][j][1] * inv, o[i][j][2] * inv, o[i][j][3] * inv);
    }
}

extern "C" void kernel_launch(void* const* d_in, const int* in_sizes, int n_in,
                              void* d_out, int out_size, void* d_ws, size_t ws_size,
                              hipStream_t stream)
{
    const float* x  = (const float*)d_in[0];
    const int* mask = (const int*)d_in[1];
    const float* Wq = (const float*)d_in[2];
    const float* bq = (const float*)d_in[3];
    const float* Wk = (const float*)d_in[4];
    const float* bk = (const float*)d_in[5];
    const float* Wv = (const float*)d_in[6];
    const float* bv = (const float*)d_in[7];
    const float* Wo = (const float*)d_in[8];
    const float* bo = (const float*)d_in[9];
    float* out = (float*)d_out;

    u16* ws = (u16*)d_ws;
    const size_t NE = (size_t)MM * DD;
    const size_t WE = (size_t)DD * DD;
    if (ws_size < 4 * NE * sizeof(u16)) return;

    u16* Qb = ws;
    u16* Kb = ws + NE;
    u16* Vb = ws + 2 * NE;
    u16* Ab = ws + 3 * NE;   // x_bf16 first, then attention output (sequential reuse)

    // W bf16 scratch lives in d_out (dead until gemm_out_k overwrites all of it)
    u16* Wscr = (u16*)d_out;          // Wq,Wk,Wv bf16: 3*WE*2 = 6 MB <= 32 MB

    dim3 blk(256);
    cvt_k<<<dim3(NE / 2048), blk, 0, stream>>>(x, Ab);
    cvtw3_k<<<dim3(WE / 2048, 3), blk, 0, stream>>>(Wq, Wk, Wv, Wscr);
    gemm_qkv_k<<<dim3(MM / 128, DD / 128, 3), blk, 0, stream>>>(
        Ab, bq, bk, bv, Wscr, Wscr + WE, Wscr + 2 * WE, Qb, Kb, Vb);
    attn_k<<<dim3(BB * HH, SS / QT), dim3(512), 0, stream>>>(Qb, Kb, Vb, mask, Ab);
    cvtw1_k<<<dim3(WE / 2048), blk, 0, stream>>>(Wo, Qb);   // Q dead; holds Wo bf16
    gemm_out_k<<<dim3(MM / 128, DD / 128), blk, 0, stream>>>(Ab, bo, Qb, out);
}